// Round 2
// baseline (323.060 us; speedup 1.0000x reference)
//
#include <hip/hip_runtime.h>
#include <hip/hip_bf16.h>
#include <stdint.h>

#define NNODES 50000
#define NEDGES 800000
#define LATENT 128
#define HIDDEN 256
#define NTYPES 32

typedef __bf16 bf16x8 __attribute__((ext_vector_type(8)));
typedef float floatx4 __attribute__((ext_vector_type(4)));

// ---------------- cast z (fp32) -> zbf (bf16). 6.4M floats = 1.6M float4.
__global__ __launch_bounds__(256) void cast_z_kernel(
    const float* __restrict__ z, __hip_bfloat16* __restrict__ zbf) {
    int i = blockIdx.x * 256 + threadIdx.x;  // one float4 per thread
    float4 v = ((const float4*)z)[i];
    __hip_bfloat16 o[4];
    o[0] = __float2bfloat16(v.x); o[1] = __float2bfloat16(v.y);
    o[2] = __float2bfloat16(v.z); o[3] = __float2bfloat16(v.w);
    *(uint2*)&zbf[(size_t)i * 4] = *(const uint2*)o;
}

// ---------------- transpose+cast W1 -> W1T[256][256] bf16, W2 -> W2Tp[16][256] bf16 (rows 8..15 zero)
__global__ __launch_bounds__(256) void transpose_kernel(
    const float* __restrict__ W1, const float* __restrict__ W2,
    __hip_bfloat16* __restrict__ W1T, __hip_bfloat16* __restrict__ W2Tp) {
    int n = blockIdx.x;   // 0..255
    int k = threadIdx.x;  // 0..255
    W1T[n * 256 + k] = __float2bfloat16(W1[k * 256 + n]);
    if (n < 16) {
        __hip_bfloat16 v = __float2bfloat16(n < 8 ? W2[k * 8 + n] : 0.f);
        W2Tp[n * 256 + k] = v;
    }
}

// ---------------- node logits: [50000,128] @ [128,32] + b  (fp32 vector)
__global__ __launch_bounds__(256) void node_kernel(
    const float* __restrict__ z, const float* __restrict__ Wn,
    const float* __restrict__ bn, float* __restrict__ out) {
    __shared__ float wt[32][132];  // transposed [type][k], padded
    __shared__ float zl[8][128];
    int t = threadIdx.x;
#pragma unroll
    for (int i = 0; i < 16; ++i) {
        int flat = t + 256 * i;  // 4096 = 128k x 32ty
        int k = flat >> 5, ty = flat & 31;
        wt[ty][k] = Wn[flat];
    }
    int node0 = blockIdx.x * 8;
    ((float4*)zl)[t] = ((const float4*)(z + (size_t)node0 * LATENT))[t];  // 256 x 16B = 8 rows
    __syncthreads();
    int ty = t & 31, ln = t >> 5;
    float acc = bn[ty];
#pragma unroll 16
    for (int k = 0; k < 128; ++k) acc += zl[ln][k] * wt[ty][k];
    out[(size_t)(node0 + ln) * NTYPES + ty] = acc;
}

// ---------------- fused edge MLP: gather(bf16) -> GEMM(256x256) -> ReLU -> GEMM(256x8)
#define EF_ROW 264   // 256 + 8 pad (bf16 elems)
#define W1T_ROW 40   // 32 + 8 pad
#define W2T_ROW 264

__global__ __launch_bounds__(256, 2) void edge_kernel(
    const __hip_bfloat16* __restrict__ zbf, const int* __restrict__ ei,
    const __hip_bfloat16* __restrict__ W1T, const float* __restrict__ b1,
    const __hip_bfloat16* __restrict__ W2T, const float* __restrict__ b2,
    float* __restrict__ out) {
    __shared__ __align__(16) __hip_bfloat16 ef[64 * EF_ROW];    // 33792 B (reused for H)
    __shared__ __align__(16) __hip_bfloat16 w1t[256 * W1T_ROW]; // 20480 B
    __shared__ __align__(16) __hip_bfloat16 w2t[16 * W2T_ROW];  // 8448 B
    __shared__ int idx2[128];

    int t = threadIdx.x;
    int e0 = blockIdx.x * 64;

    // int64-vs-int32 edge_index detection: int64 hi-words (odd int32 positions) are all 0.
    bool i64 = ((ei[1] | ei[3] | ei[5] | ei[7] | ei[9] | ei[11] | ei[13] | ei[15]) == 0);

    if (t < 64) {
        int e = e0 + t;
        idx2[t] = i64 ? ei[2 * e] : ei[e];                    // row indices
    } else if (t < 128) {
        int e = e0 + (t - 64);
        idx2[t] = i64 ? ei[2 * (NEDGES + e)] : ei[NEDGES + e]; // col indices
    }

    {   // stage W2T (once): 16 rows x 256 bf16 = 512 x 16B
        const uint4* src = (const uint4*)W2T;
#pragma unroll
        for (int i = 0; i < 2; ++i) {
            int p = t + 256 * i;
            int n = p >> 5, c = p & 31;
            *(uint4*)&w2t[n * W2T_ROW + c * 8] = src[p];
        }
    }
    __syncthreads();  // idx2 ready

    {   // gather edge features: 64 edges x 2 halves x 16 chunks(16B)
#pragma unroll
        for (int i = 0; i < 8; ++i) {
            int p = i * 256 + t;
            int e = p >> 5;
            int r = p & 31;
            int half = r >> 4, c = r & 15;
            int node = idx2[half * 64 + e];
            const uint4* src = (const uint4*)(zbf + (size_t)node * LATENT);
            *(uint4*)&ef[e * EF_ROW + half * 128 + c * 8] = src[c];
        }
    }

    int lane = t & 63, wave = t >> 6;
    int l16 = lane & 15, quad = lane >> 4;
    int nb = wave * 64;  // this wave's N range in [0,256)

    floatx4 acc[4][4];
#pragma unroll
    for (int a = 0; a < 4; ++a)
#pragma unroll
        for (int b = 0; b < 4; ++b) acc[a][b] = floatx4{0.f, 0.f, 0.f, 0.f};

    for (int kt = 0; kt < 8; ++kt) {
        int k0 = kt * 32;
        __syncthreads();  // kt==0: ef writes done; kt>0: prior frag reads done
        {   // stage W1T k-tile: [256 n][32 k]
#pragma unroll
            for (int i = 0; i < 4; ++i) {
                int p = t + 256 * i;  // 1024 x 16B
                int n = p >> 2, c = p & 3;
                *(uint4*)&w1t[n * W1T_ROW + c * 8] = *(const uint4*)&W1T[n * 256 + k0 + c * 8];
            }
        }
        __syncthreads();
        bf16x8 bfrag[4], afrag[4];
#pragma unroll
        for (int nt = 0; nt < 4; ++nt)
            bfrag[nt] = *(const bf16x8*)&w1t[(nb + nt * 16 + l16) * W1T_ROW + quad * 8];
#pragma unroll
        for (int mt = 0; mt < 4; ++mt)
            afrag[mt] = *(const bf16x8*)&ef[(mt * 16 + l16) * EF_ROW + k0 + quad * 8];
#pragma unroll
        for (int mt = 0; mt < 4; ++mt)
#pragma unroll
            for (int nt = 0; nt < 4; ++nt)
                acc[mt][nt] = __builtin_amdgcn_mfma_f32_16x16x32_bf16(
                    afrag[mt], bfrag[nt], acc[mt][nt], 0, 0, 0);
    }

    float b1v[4];
#pragma unroll
    for (int nt = 0; nt < 4; ++nt) b1v[nt] = b1[nb + nt * 16 + l16];

    __syncthreads();  // all ef reads done -> safe to overwrite with H
#pragma unroll
    for (int mt = 0; mt < 4; ++mt)
#pragma unroll
        for (int nt = 0; nt < 4; ++nt)
#pragma unroll
            for (int r = 0; r < 4; ++r) {
                float v = acc[mt][nt][r] + b1v[nt];
                v = v > 0.f ? v : 0.f;
                int row = mt * 16 + quad * 4 + r;     // edge (local)
                int col = nb + nt * 16 + l16;         // hidden dim
                ef[row * EF_ROW + col] = __float2bfloat16(v);
            }
    __syncthreads();

    // layer 2: each wave takes one m-tile of 16 edges; N=16 (cols 8..15 zero-padded)
    floatx4 acc2 = floatx4{0.f, 0.f, 0.f, 0.f};
#pragma unroll
    for (int kt = 0; kt < 8; ++kt) {
        int k0 = kt * 32;
        bf16x8 a2 = *(const bf16x8*)&ef[(wave * 16 + l16) * EF_ROW + k0 + quad * 8];
        bf16x8 b2f = *(const bf16x8*)&w2t[l16 * W2T_ROW + k0 + quad * 8];
        acc2 = __builtin_amdgcn_mfma_f32_16x16x32_bf16(a2, b2f, acc2, 0, 0, 0);
    }
    if (l16 < 8) {
        float bb = b2[l16];
#pragma unroll
        for (int r = 0; r < 4; ++r) {
            int erow = e0 + wave * 16 + quad * 4 + r;
            out[(size_t)erow * 8 + l16] = acc2[r] + bb;
        }
    }
}

extern "C" void kernel_launch(void* const* d_in, const int* in_sizes, int n_in,
                              void* d_out, int out_size, void* d_ws, size_t ws_size,
                              hipStream_t stream) {
    const float* z  = (const float*)d_in[0];
    const int* ei   = (const int*)d_in[1];
    const float* Wn = (const float*)d_in[2];
    const float* bn = (const float*)d_in[3];
    const float* W1 = (const float*)d_in[4];
    const float* b1 = (const float*)d_in[5];
    const float* W2 = (const float*)d_in[6];
    const float* b2 = (const float*)d_in[7];
    float* out = (float*)d_out;

    __hip_bfloat16* zbf  = (__hip_bfloat16*)d_ws;            // 6,400,000 bf16
    __hip_bfloat16* W1T  = zbf + (size_t)NNODES * LATENT;    // 65,536 bf16
    __hip_bfloat16* W2Tp = W1T + 256 * 256;                  // 4,096 bf16

    hipLaunchKernelGGL(cast_z_kernel, dim3(NNODES * LATENT / 1024), dim3(256), 0, stream, z, zbf);
    hipLaunchKernelGGL(transpose_kernel, dim3(256), dim3(256), 0, stream, W1, W2, W1T, W2Tp);
    hipLaunchKernelGGL(node_kernel, dim3(NNODES / 8), dim3(256), 0, stream, z, Wn, bn, out);
    hipLaunchKernelGGL(edge_kernel, dim3(NEDGES / 64), dim3(256), 0, stream,
                       zbf, ei, W1T, b1, W2Tp, b2, out + (size_t)NNODES * NTYPES);
}